// Round 1
// baseline (4261.537 us; speedup 1.0000x reference)
//
#include <hip/hip_runtime.h>
#include <hip/hip_bf16.h>

typedef __attribute__((ext_vector_type(4))) float  f32x4;
typedef __attribute__((ext_vector_type(8))) __bf16 bf16x8;

#define H_DIM 256
#define SEQ   64
#define TDEC  32
#define BB    16
#define NTH   512

// ws layout (bf16 element offsets)
#define OW0 0u         // enc_Whh0 [1024][256]
#define OW1 262144u    // enc_Wih1
#define OW2 524288u    // enc_Whh1
#define OW3 786432u    // dec_Whh0
#define OW4 1048576u   // dec_Wih1
#define OW5 1310720u   // dec_Whh1
#define OW6 1572864u   // Wp1 [128][256]
#define OW7 1605632u   // Wp2 padded [16][128] (rows 4..15 zero)
#define WS_ELEMS 1607680u

__global__ void prep_kernel(const float* __restrict__ s0, const float* __restrict__ s1,
                            const float* __restrict__ s2, const float* __restrict__ s3,
                            const float* __restrict__ s4, const float* __restrict__ s5,
                            const float* __restrict__ s6, const float* __restrict__ s7,
                            ushort* __restrict__ o) {
  unsigned i = blockIdx.x * 256u + threadIdx.x;
  if (i >= WS_ELEMS) return;
  float v;
  if (i < OW6) {
    unsigned m = i >> 18, r = i & 262143u;
    const float* s = (m==0)?s0:(m==1)?s1:(m==2)?s2:(m==3)?s3:(m==4)?s4:s5;
    v = s[r];
  } else if (i < OW7) {
    v = s6[i - OW6];
  } else {
    unsigned r = i - OW7, n = r >> 7, k = r & 127u;
    v = (n < 4u) ? s7[n*128u + k] : 0.0f;
  }
  __bf16 b = (__bf16)v;
  o[i] = __builtin_bit_cast(ushort, b);
}

__device__ __forceinline__ float sig_(float x) {
  return __builtin_amdgcn_rcpf(1.0f + __expf(-x));
}
__device__ __forceinline__ float tanh_(float x) {
  // tanh(x) = 1 - 2/(exp(2x)+1); saturates correctly at +-inf
  return 1.0f - 2.0f * __builtin_amdgcn_rcpf(__expf(2.0f*x) + 1.0f);
}
// swizzled element index for a [16][stride] bf16 LDS tile: 16B-slot XORed with row&7
__device__ __forceinline__ int swz(int row, int n, int stride) {
  return row*stride + (((n >> 3) ^ (row & 7)) << 3) + (n & 7);
}
// A-fragment read: lane holds A[row=lane&15][k = k0 + (lane>>4)*8 .. +7]
__device__ __forceinline__ bf16x8 ldlds(const ushort* buf, int row, int u, int stride) {
  return *(const bf16x8*)(buf + row*stride + ((u ^ (row & 7)) << 3));
}

__global__ __launch_bounds__(NTH, 2) void lstm_all(
    const float* __restrict__ x,
    const float* __restrict__ eWih0, const float* __restrict__ eb0, const float* __restrict__ eb1,
    const float* __restrict__ dWih0, const float* __restrict__ db0, const float* __restrict__ db1,
    const float* __restrict__ bp1, const float* __restrict__ bp2,
    const ushort* __restrict__ ws,
    float* __restrict__ out)
{
  const int tid  = threadIdx.x;
  const int wv   = tid >> 6;      // wave 0..7
  const int lane = tid & 63;
  const int col  = lane & 15;     // MFMA 16-dim index
  const int quad = lane >> 4;     // 0..3
  const int koff = quad << 3;     // per-lane K offset within fragment
  const int blk  = blockIdx.x;
  const int n0   = wv*32 + col;   // gate-aligned column slice base (st adds 16)
  const int n0p  = wv*16 + col;   // MLP hidden column

  __shared__ __align__(16) ushort sh_h0[2][BB*H_DIM];
  __shared__ __align__(16) ushort sh_h1[2][BB*H_DIM];
  __shared__ __align__(16) ushort sh_r[BB*128];
  __shared__ __align__(16) float  sh_x[SEQ*BB*4];   // [t][b][k]
  __shared__ __align__(16) float  sh_pred[BB*4];

  // preload this block's x slice (contiguous 4096 floats), transpose to [t][b][k]
  for (int i = tid; i < SEQ*BB*4; i += NTH) {
    int b = i >> 8, tk = i & 255;
    sh_x[(tk>>2)*64 + b*4 + (tk&3)] = x[blk*(SEQ*BB*4) + i];
  }
  for (int i = tid; i < BB*H_DIM; i += NTH) {
    sh_h0[0][i]=0; sh_h0[1][i]=0; sh_h1[0][i]=0; sh_h1[1][i]=0;
  }
  __syncthreads();

  float c0[2][4] = {{0,0,0,0},{0,0,0,0}};
  float c1[2][4] = {{0,0,0,0},{0,0,0,0}};
  int cur = 0;

  // per-lane weight fragment base pointers (row n0 / n0p, K-phase koff)
  const ushort* Wb0 = ws + OW0 + n0*H_DIM + koff;
  const ushort* Wb1 = ws + OW1 + n0*H_DIM + koff;
  const ushort* Wb2 = ws + OW2 + n0*H_DIM + koff;
  const ushort* Wb3 = ws + OW3 + n0*H_DIM + koff;
  const ushort* Wb4 = ws + OW4 + n0*H_DIM + koff;
  const ushort* Wb5 = ws + OW5 + n0*H_DIM + koff;
  const ushort* Wb6 = ws + OW6 + n0p*H_DIM + koff;
  const ushort* Wb7 = ws + OW7 + col*128 + koff;

  // ================= ENCODER =================
  for (int t = 0; t < SEQ; ++t) {
    // ---- layer 0 ----
    f32x4 xv[4];
    #pragma unroll
    for (int r = 0; r < 4; ++r)
      xv[r] = *(const f32x4*)(sh_x + t*64 + (quad*4+r)*4);

    f32x4 acc[4][2];
    #pragma unroll
    for (int g = 0; g < 4; ++g)
      #pragma unroll
      for (int st = 0; st < 2; ++st) {
        int j = g*256 + st*16 + n0;
        f32x4 wvv = *(const f32x4*)(eWih0 + j*4);
        float bz = eb0[j];
        #pragma unroll
        for (int r = 0; r < 4; ++r)
          acc[g][st][r] = bz + wvv[0]*xv[r][0] + wvv[1]*xv[r][1]
                             + wvv[2]*xv[r][2] + wvv[3]*xv[r][3];
      }
    {
      const ushort* h0c = sh_h0[cur];
      #pragma unroll 2
      for (int k0 = 0; k0 < H_DIM; k0 += 32) {
        bf16x8 af = ldlds(h0c, col, (k0>>3)+quad, H_DIM);
        #pragma unroll
        for (int g = 0; g < 4; ++g)
          #pragma unroll
          for (int st = 0; st < 2; ++st)
            acc[g][st] = __builtin_amdgcn_mfma_f32_16x16x32_bf16(
                af, *(const bf16x8*)(Wb0 + g*65536 + st*4096 + k0), acc[g][st], 0, 0, 0);
      }
    }
    ushort* h0n = sh_h0[cur^1];
    #pragma unroll
    for (int st = 0; st < 2; ++st)
      #pragma unroll
      for (int r = 0; r < 4; ++r) {
        float iv = sig_(acc[0][st][r]);
        float fv = sig_(acc[1][st][r]);
        float gv = tanh_(acc[2][st][r]);
        float ov = sig_(acc[3][st][r]);
        float cn = fv*c0[st][r] + iv*gv;
        c0[st][r] = cn;
        float hn = ov*tanh_(cn);
        __bf16 hb = (__bf16)hn;
        h0n[swz(quad*4+r, st*16 + n0, H_DIM)] = __builtin_bit_cast(ushort, hb);
      }
    __syncthreads();

    // ---- layer 1 ----
    f32x4 acc1[4][2];
    #pragma unroll
    for (int g = 0; g < 4; ++g)
      #pragma unroll
      for (int st = 0; st < 2; ++st) {
        float bz = eb1[g*256 + st*16 + n0];
        f32x4 v; v[0]=bz; v[1]=bz; v[2]=bz; v[3]=bz;
        acc1[g][st] = v;
      }
    {
      #pragma unroll 2
      for (int k0 = 0; k0 < H_DIM; k0 += 32) {
        bf16x8 af = ldlds(h0n, col, (k0>>3)+quad, H_DIM);
        #pragma unroll
        for (int g = 0; g < 4; ++g)
          #pragma unroll
          for (int st = 0; st < 2; ++st)
            acc1[g][st] = __builtin_amdgcn_mfma_f32_16x16x32_bf16(
                af, *(const bf16x8*)(Wb1 + g*65536 + st*4096 + k0), acc1[g][st], 0, 0, 0);
      }
      const ushort* h1c = sh_h1[cur];
      #pragma unroll 2
      for (int k0 = 0; k0 < H_DIM; k0 += 32) {
        bf16x8 af = ldlds(h1c, col, (k0>>3)+quad, H_DIM);
        #pragma unroll
        for (int g = 0; g < 4; ++g)
          #pragma unroll
          for (int st = 0; st < 2; ++st)
            acc1[g][st] = __builtin_amdgcn_mfma_f32_16x16x32_bf16(
                af, *(const bf16x8*)(Wb2 + g*65536 + st*4096 + k0), acc1[g][st], 0, 0, 0);
      }
    }
    ushort* h1n = sh_h1[cur^1];
    #pragma unroll
    for (int st = 0; st < 2; ++st)
      #pragma unroll
      for (int r = 0; r < 4; ++r) {
        float iv = sig_(acc1[0][st][r]);
        float fv = sig_(acc1[1][st][r]);
        float gv = tanh_(acc1[2][st][r]);
        float ov = sig_(acc1[3][st][r]);
        float cn = fv*c1[st][r] + iv*gv;
        c1[st][r] = cn;
        float hn = ov*tanh_(cn);
        __bf16 hb = (__bf16)hn;
        h1n[swz(quad*4+r, st*16 + n0, H_DIM)] = __builtin_bit_cast(ushort, hb);
      }
    // no end-of-step barrier needed: next step's mid-step barrier orders all hazards
    cur ^= 1;
  }

  // ================= DECODER =================
  if (tid < 64) sh_pred[tid] = sh_x[63*64 + tid];  // x[:, -1, :]
  __syncthreads();

  for (int t = 0; t < TDEC; ++t) {
    // ---- layer 0 (input = pred, dim 4) ----
    f32x4 pv[4];
    #pragma unroll
    for (int r = 0; r < 4; ++r)
      pv[r] = *(const f32x4*)(sh_pred + (quad*4+r)*4);

    f32x4 acc[4][2];
    #pragma unroll
    for (int g = 0; g < 4; ++g)
      #pragma unroll
      for (int st = 0; st < 2; ++st) {
        int j = g*256 + st*16 + n0;
        f32x4 wvv = *(const f32x4*)(dWih0 + j*4);
        float bz = db0[j];
        #pragma unroll
        for (int r = 0; r < 4; ++r)
          acc[g][st][r] = bz + wvv[0]*pv[r][0] + wvv[1]*pv[r][1]
                             + wvv[2]*pv[r][2] + wvv[3]*pv[r][3];
      }
    {
      const ushort* h0c = sh_h0[cur];
      #pragma unroll 2
      for (int k0 = 0; k0 < H_DIM; k0 += 32) {
        bf16x8 af = ldlds(h0c, col, (k0>>3)+quad, H_DIM);
        #pragma unroll
        for (int g = 0; g < 4; ++g)
          #pragma unroll
          for (int st = 0; st < 2; ++st)
            acc[g][st] = __builtin_amdgcn_mfma_f32_16x16x32_bf16(
                af, *(const bf16x8*)(Wb3 + g*65536 + st*4096 + k0), acc[g][st], 0, 0, 0);
      }
    }
    ushort* h0n = sh_h0[cur^1];
    #pragma unroll
    for (int st = 0; st < 2; ++st)
      #pragma unroll
      for (int r = 0; r < 4; ++r) {
        float iv = sig_(acc[0][st][r]);
        float fv = sig_(acc[1][st][r]);
        float gv = tanh_(acc[2][st][r]);
        float ov = sig_(acc[3][st][r]);
        float cn = fv*c0[st][r] + iv*gv;
        c0[st][r] = cn;
        float hn = ov*tanh_(cn);
        __bf16 hb = (__bf16)hn;
        h0n[swz(quad*4+r, st*16 + n0, H_DIM)] = __builtin_bit_cast(ushort, hb);
      }
    __syncthreads();

    // ---- layer 1 ----
    f32x4 acc1[4][2];
    #pragma unroll
    for (int g = 0; g < 4; ++g)
      #pragma unroll
      for (int st = 0; st < 2; ++st) {
        float bz = db1[g*256 + st*16 + n0];
        f32x4 v; v[0]=bz; v[1]=bz; v[2]=bz; v[3]=bz;
        acc1[g][st] = v;
      }
    {
      #pragma unroll 2
      for (int k0 = 0; k0 < H_DIM; k0 += 32) {
        bf16x8 af = ldlds(h0n, col, (k0>>3)+quad, H_DIM);
        #pragma unroll
        for (int g = 0; g < 4; ++g)
          #pragma unroll
          for (int st = 0; st < 2; ++st)
            acc1[g][st] = __builtin_amdgcn_mfma_f32_16x16x32_bf16(
                af, *(const bf16x8*)(Wb4 + g*65536 + st*4096 + k0), acc1[g][st], 0, 0, 0);
      }
      const ushort* h1c = sh_h1[cur];
      #pragma unroll 2
      for (int k0 = 0; k0 < H_DIM; k0 += 32) {
        bf16x8 af = ldlds(h1c, col, (k0>>3)+quad, H_DIM);
        #pragma unroll
        for (int g = 0; g < 4; ++g)
          #pragma unroll
          for (int st = 0; st < 2; ++st)
            acc1[g][st] = __builtin_amdgcn_mfma_f32_16x16x32_bf16(
                af, *(const bf16x8*)(Wb5 + g*65536 + st*4096 + k0), acc1[g][st], 0, 0, 0);
      }
    }
    ushort* h1n = sh_h1[cur^1];
    #pragma unroll
    for (int st = 0; st < 2; ++st)
      #pragma unroll
      for (int r = 0; r < 4; ++r) {
        float iv = sig_(acc1[0][st][r]);
        float fv = sig_(acc1[1][st][r]);
        float gv = tanh_(acc1[2][st][r]);
        float ov = sig_(acc1[3][st][r]);
        float cn = fv*c1[st][r] + iv*gv;
        c1[st][r] = cn;
        float hn = ov*tanh_(cn);
        __bf16 hb = (__bf16)hn;
        h1n[swz(quad*4+r, st*16 + n0, H_DIM)] = __builtin_bit_cast(ushort, hb);
      }
    __syncthreads();

    // ---- MLP layer 1: [16,256] @ Wp1^T -> relu -> sh_r [16][128] ----
    {
      float bz = bp1[n0p];
      f32x4 accp; accp[0]=bz; accp[1]=bz; accp[2]=bz; accp[3]=bz;
      const ushort* h1r = sh_h1[cur^1];
      #pragma unroll 2
      for (int k0 = 0; k0 < H_DIM; k0 += 32) {
        bf16x8 af = ldlds(h1r, col, (k0>>3)+quad, H_DIM);
        accp = __builtin_amdgcn_mfma_f32_16x16x32_bf16(
            af, *(const bf16x8*)(Wb6 + k0), accp, 0, 0, 0);
      }
      #pragma unroll
      for (int r = 0; r < 4; ++r) {
        float rv = fmaxf(accp[r], 0.0f);
        __bf16 rb = (__bf16)rv;
        sh_r[swz(quad*4+r, n0p, 128)] = __builtin_bit_cast(ushort, rb);
      }
    }
    __syncthreads();

    // ---- MLP layer 2 (wave 0): [16,128] @ Wp2pad^T, cols 0..3 valid ----
    if (wv == 0) {
      f32x4 accq; accq[0]=0; accq[1]=0; accq[2]=0; accq[3]=0;
      #pragma unroll
      for (int k0 = 0; k0 < 128; k0 += 32) {
        bf16x8 af = ldlds(sh_r, col, (k0>>3)+quad, 128);
        accq = __builtin_amdgcn_mfma_f32_16x16x32_bf16(
            af, *(const bf16x8*)(Wb7 + k0), accq, 0, 0, 0);
      }
      if (col < 4) {
        float bo = bp2[col];
        #pragma unroll
        for (int r = 0; r < 4; ++r) {
          float p = sig_(accq[r] + bo);
          int b = quad*4 + r;
          sh_pred[b*4 + col] = p;
          out[((blk*BB + b)*TDEC + t)*4 + col] = p;
        }
      }
    }
    __syncthreads();
    cur ^= 1;
  }
}

extern "C" void kernel_launch(void* const* d_in, const int* in_sizes, int n_in,
                              void* d_out, int out_size, void* d_ws, size_t ws_size,
                              hipStream_t stream) {
  (void)in_sizes; (void)n_in; (void)out_size;
  if (ws_size < (size_t)WS_ELEMS * sizeof(ushort)) return;  // need ~3.1 MB scratch

  const float* x      = (const float*)d_in[0];
  const float* eWih0  = (const float*)d_in[1];
  const float* eWhh0  = (const float*)d_in[2];
  const float* eb0    = (const float*)d_in[3];
  const float* eWih1  = (const float*)d_in[4];
  const float* eWhh1  = (const float*)d_in[5];
  const float* eb1    = (const float*)d_in[6];
  const float* dWih0  = (const float*)d_in[7];
  const float* dWhh0  = (const float*)d_in[8];
  const float* db0    = (const float*)d_in[9];
  const float* dWih1  = (const float*)d_in[10];
  const float* dWhh1  = (const float*)d_in[11];
  const float* db1    = (const float*)d_in[12];
  const float* Wp1    = (const float*)d_in[13];
  const float* bp1    = (const float*)d_in[14];
  const float* Wp2    = (const float*)d_in[15];
  const float* bp2    = (const float*)d_in[16];
  ushort* ws = (ushort*)d_ws;

  prep_kernel<<<WS_ELEMS/256, 256, 0, stream>>>(eWhh0, eWih1, eWhh1, dWhh0, dWih1, dWhh1,
                                                Wp1, Wp2, ws);
  lstm_all<<<256, NTH, 0, stream>>>(x, eWih0, eb0, eb1, dWih0, db0, db1,
                                    bp1, bp2, ws, (float*)d_out);
}

// Round 2
// 2113.408 us; speedup vs baseline: 2.0164x; 2.0164x over previous
//
#include <hip/hip_runtime.h>
#include <hip/hip_bf16.h>

typedef __attribute__((ext_vector_type(4))) float  f32x4;
typedef __attribute__((ext_vector_type(8))) __bf16 bf16x8;

#define H_DIM 256
#define SEQ   64
#define TDEC  32
#define BB    16
#define NTH   512

// ws layout (bf16 element offsets). Six big matrices stored in MFMA-fragment
// order: elem = w*32768 + k0i*4096 + gs*512 + lane*8 + e
//   row = g*256 + st*16 + w*32 + (lane&15), col = k0i*32 + (lane>>4)*8 + e
#define OW0 0u         // enc_Whh0
#define OW1 262144u    // enc_Wih1
#define OW2 524288u    // enc_Whh1
#define OW3 786432u    // dec_Whh0
#define OW4 1048576u   // dec_Wih1
#define OW5 1310720u   // dec_Whh1
#define OW6 1572864u   // Wp1: w*4096 + k0i*512 + lane*8 + e ; row=w*16+(lane&15)
#define OW7 1605632u   // Wp2 padded [16][128]: k0i*512 + lane*8 + e ; row=lane&15
#define WS_ELEMS 1607680u

__global__ void prep_kernel(const float* __restrict__ s0, const float* __restrict__ s1,
                            const float* __restrict__ s2, const float* __restrict__ s3,
                            const float* __restrict__ s4, const float* __restrict__ s5,
                            const float* __restrict__ s6, const float* __restrict__ s7,
                            ushort* __restrict__ o) {
  unsigned i = blockIdx.x * 256u + threadIdx.x;
  if (i >= WS_ELEMS) return;
  float v;
  if (i < OW6) {
    unsigned m = i >> 18, r = i & 262143u;
    unsigned w = r >> 15, r2 = r & 32767u;
    unsigned k0i = r2 >> 12, r3 = r2 & 4095u;
    unsigned gs = r3 >> 9, r4 = r3 & 511u;
    unsigned lane = r4 >> 3, e = r4 & 7u;
    unsigned row = (gs >> 1) * 256u + (gs & 1u) * 16u + w * 32u + (lane & 15u);
    unsigned colk = k0i * 32u + (lane >> 4) * 8u + e;
    const float* s = (m==0)?s0:(m==1)?s1:(m==2)?s2:(m==3)?s3:(m==4)?s4:s5;
    v = s[row * 256u + colk];
  } else if (i < OW7) {
    unsigned r = i - OW6;
    unsigned w = r >> 12, r2 = r & 4095u;
    unsigned k0i = r2 >> 9, r3 = r2 & 511u;
    unsigned lane = r3 >> 3, e = r3 & 7u;
    unsigned row = w * 16u + (lane & 15u);
    unsigned colk = k0i * 32u + (lane >> 4) * 8u + e;
    v = s6[row * 256u + colk];
  } else {
    unsigned r = i - OW7;
    unsigned k0i = r >> 9, r3 = r & 511u;
    unsigned lane = r3 >> 3, e = r3 & 7u;
    unsigned row = lane & 15u;
    unsigned colk = k0i * 32u + (lane >> 4) * 8u + e;
    v = (row < 4u) ? s7[row * 128u + colk] : 0.0f;
  }
  __bf16 b = (__bf16)v;
  o[i] = __builtin_bit_cast(ushort, b);
}

__device__ __forceinline__ float sig_(float x) {
  return __builtin_amdgcn_rcpf(1.0f + __expf(-x));
}
__device__ __forceinline__ float tanh_(float x) {
  return 1.0f - 2.0f * __builtin_amdgcn_rcpf(__expf(2.0f*x) + 1.0f);
}
// 32-slot swizzle: granule u of row stored at slot (u + 4*(row&7)) & 31.
// Wave read (16 rows x 4 quads) -> 32 slots x 2 lanes = conflict-free.
__device__ __forceinline__ int swz32(int row, int n) {
  return row*H_DIM + ((((n >> 3) + 4*(row & 7)) & 31) << 3) + (n & 7);
}
__device__ __forceinline__ bf16x8 ldh(const ushort* buf, int row, int u) {
  return *(const bf16x8*)(buf + row*H_DIM + (((u + 4*(row & 7)) & 31) << 3));
}

__global__ __launch_bounds__(NTH, 2) void lstm_all(
    const float* __restrict__ x,
    const float* __restrict__ eWih0, const float* __restrict__ eb0, const float* __restrict__ eb1,
    const float* __restrict__ dWih0, const float* __restrict__ db0, const float* __restrict__ db1,
    const float* __restrict__ bp1, const float* __restrict__ bp2,
    const ushort* __restrict__ ws,
    float* __restrict__ out)
{
  const int tid  = threadIdx.x;
  const int wv   = tid >> 6;
  const int lane = tid & 63;
  const int col  = lane & 15;
  const int quad = lane >> 4;
  const int blk  = blockIdx.x;
  const int n0   = wv*32 + col;
  const int rot  = blk & 7;

  __shared__ __align__(16) ushort sh_h0[2][BB*H_DIM];
  __shared__ __align__(16) ushort sh_h1[2][BB*H_DIM];
  __shared__ __align__(16) ushort sh_r[BB*H_DIM];   // MLP hidden, stride 256 (cols 0..127 used)
  __shared__ __align__(16) float  sh_x[SEQ*BB*4];   // [t][b][k]
  __shared__ __align__(16) float  sh_pred[BB*4];

  for (int i = tid; i < SEQ*BB*4; i += NTH) {
    int b = i >> 8, tk = i & 255;
    sh_x[(tk>>2)*64 + b*4 + (tk&3)] = x[blk*(SEQ*BB*4) + i];
  }
  for (int i = tid; i < BB*H_DIM; i += NTH) {
    sh_h0[0][i]=0; sh_h0[1][i]=0; sh_h1[0][i]=0; sh_h1[1][i]=0;
  }
  __syncthreads();

  float c0[2][4] = {{0,0,0,0},{0,0,0,0}};
  float c1[2][4] = {{0,0,0,0},{0,0,0,0}};
  int cur = 0;

  // per-lane fragment bases (fragment-ordered layout: + k0i*4096 + gs*512)
  const ushort* B0 = ws + OW0 + wv*32768 + lane*8;
  const ushort* B1 = ws + OW1 + wv*32768 + lane*8;
  const ushort* B2 = ws + OW2 + wv*32768 + lane*8;
  const ushort* B3 = ws + OW3 + wv*32768 + lane*8;
  const ushort* B4 = ws + OW4 + wv*32768 + lane*8;
  const ushort* B5 = ws + OW5 + wv*32768 + lane*8;
  const ushort* B6 = ws + OW6 + wv*4096  + lane*8;
  const ushort* B7 = ws + OW7 + lane*8;

  // ================= ENCODER =================
  {
    // hoist x-projection weights + biases into registers
    f32x4 eW0v[8]; float eb0v[8], eb1v[8];
    #pragma unroll
    for (int gs = 0; gs < 8; ++gs) {
      int j = (gs>>1)*256 + (gs&1)*16 + n0;
      eW0v[gs] = *(const f32x4*)(eWih0 + j*4);
      eb0v[gs] = eb0[j];
      eb1v[gs] = eb1[j];
    }

    for (int t = 0; t < SEQ; ++t) {
      // ---- layer 0 ----
      f32x4 xv[4];
      #pragma unroll
      for (int r = 0; r < 4; ++r)
        xv[r] = *(const f32x4*)(sh_x + t*64 + (quad*4+r)*4);

      f32x4 acc[8];
      #pragma unroll
      for (int gs = 0; gs < 8; ++gs) {
        f32x4 wvv = eW0v[gs]; float bz = eb0v[gs];
        #pragma unroll
        for (int r = 0; r < 4; ++r)
          acc[gs][r] = bz + wvv[0]*xv[r][0] + wvv[1]*xv[r][1]
                          + wvv[2]*xv[r][2] + wvv[3]*xv[r][3];
      }
      {
        const ushort* h0c = sh_h0[cur];
        #pragma unroll 2
        for (int it = 0; it < 8; ++it) {
          int k0i = (it + rot) & 7;
          bf16x8 af = ldh(h0c, col, k0i*4 + quad);
          const ushort* bp = B0 + k0i*4096;
          #pragma unroll
          for (int gs = 0; gs < 8; ++gs)
            acc[gs] = __builtin_amdgcn_mfma_f32_16x16x32_bf16(
                af, *(const bf16x8*)(bp + gs*512), acc[gs], 0, 0, 0);
        }
      }
      ushort* h0n = sh_h0[cur^1];
      #pragma unroll
      for (int st = 0; st < 2; ++st)
        #pragma unroll
        for (int r = 0; r < 4; ++r) {
          float iv = sig_(acc[0+st][r]);
          float fv = sig_(acc[2+st][r]);
          float gv = tanh_(acc[4+st][r]);
          float ov = sig_(acc[6+st][r]);
          float cn = fv*c0[st][r] + iv*gv;
          c0[st][r] = cn;
          float hn = ov*tanh_(cn);
          __bf16 hb = (__bf16)hn;
          h0n[swz32(quad*4+r, st*16 + n0)] = __builtin_bit_cast(ushort, hb);
        }
      __syncthreads();

      // ---- layer 1 ----
      f32x4 acc1[8];
      #pragma unroll
      for (int gs = 0; gs < 8; ++gs) {
        float bz = eb1v[gs];
        f32x4 v; v[0]=bz; v[1]=bz; v[2]=bz; v[3]=bz;
        acc1[gs] = v;
      }
      {
        #pragma unroll 2
        for (int it = 0; it < 8; ++it) {
          int k0i = (it + rot) & 7;
          bf16x8 af = ldh(h0n, col, k0i*4 + quad);
          const ushort* bp = B1 + k0i*4096;
          #pragma unroll
          for (int gs = 0; gs < 8; ++gs)
            acc1[gs] = __builtin_amdgcn_mfma_f32_16x16x32_bf16(
                af, *(const bf16x8*)(bp + gs*512), acc1[gs], 0, 0, 0);
        }
        const ushort* h1c = sh_h1[cur];
        #pragma unroll 2
        for (int it = 0; it < 8; ++it) {
          int k0i = (it + rot) & 7;
          bf16x8 af = ldh(h1c, col, k0i*4 + quad);
          const ushort* bp = B2 + k0i*4096;
          #pragma unroll
          for (int gs = 0; gs < 8; ++gs)
            acc1[gs] = __builtin_amdgcn_mfma_f32_16x16x32_bf16(
                af, *(const bf16x8*)(bp + gs*512), acc1[gs], 0, 0, 0);
        }
      }
      ushort* h1n = sh_h1[cur^1];
      #pragma unroll
      for (int st = 0; st < 2; ++st)
        #pragma unroll
        for (int r = 0; r < 4; ++r) {
          float iv = sig_(acc1[0+st][r]);
          float fv = sig_(acc1[2+st][r]);
          float gv = tanh_(acc1[4+st][r]);
          float ov = sig_(acc1[6+st][r]);
          float cn = fv*c1[st][r] + iv*gv;
          c1[st][r] = cn;
          float hn = ov*tanh_(cn);
          __bf16 hb = (__bf16)hn;
          h1n[swz32(quad*4+r, st*16 + n0)] = __builtin_bit_cast(ushort, hb);
        }
      cur ^= 1;
    }
  }

  // ================= DECODER =================
  if (tid < 64) sh_pred[tid] = sh_x[63*64 + tid];
  __syncthreads();

  {
    f32x4 dW0v[8]; float db0v[8], db1v[8];
    #pragma unroll
    for (int gs = 0; gs < 8; ++gs) {
      int j = (gs>>1)*256 + (gs&1)*16 + n0;
      dW0v[gs] = *(const f32x4*)(dWih0 + j*4);
      db0v[gs] = db0[j];
      db1v[gs] = db1[j];
    }
    const float bz1 = bp1[wv*16 + col];

    for (int t = 0; t < TDEC; ++t) {
      // ---- layer 0 ----
      f32x4 pv[4];
      #pragma unroll
      for (int r = 0; r < 4; ++r)
        pv[r] = *(const f32x4*)(sh_pred + (quad*4+r)*4);

      f32x4 acc[8];
      #pragma unroll
      for (int gs = 0; gs < 8; ++gs) {
        f32x4 wvv = dW0v[gs]; float bz = db0v[gs];
        #pragma unroll
        for (int r = 0; r < 4; ++r)
          acc[gs][r] = bz + wvv[0]*pv[r][0] + wvv[1]*pv[r][1]
                          + wvv[2]*pv[r][2] + wvv[3]*pv[r][3];
      }
      {
        const ushort* h0c = sh_h0[cur];
        #pragma unroll 2
        for (int it = 0; it < 8; ++it) {
          int k0i = (it + rot) & 7;
          bf16x8 af = ldh(h0c, col, k0i*4 + quad);
          const ushort* bp = B3 + k0i*4096;
          #pragma unroll
          for (int gs = 0; gs < 8; ++gs)
            acc[gs] = __builtin_amdgcn_mfma_f32_16x16x32_bf16(
                af, *(const bf16x8*)(bp + gs*512), acc[gs], 0, 0, 0);
        }
      }
      ushort* h0n = sh_h0[cur^1];
      #pragma unroll
      for (int st = 0; st < 2; ++st)
        #pragma unroll
        for (int r = 0; r < 4; ++r) {
          float iv = sig_(acc[0+st][r]);
          float fv = sig_(acc[2+st][r]);
          float gv = tanh_(acc[4+st][r]);
          float ov = sig_(acc[6+st][r]);
          float cn = fv*c0[st][r] + iv*gv;
          c0[st][r] = cn;
          float hn = ov*tanh_(cn);
          __bf16 hb = (__bf16)hn;
          h0n[swz32(quad*4+r, st*16 + n0)] = __builtin_bit_cast(ushort, hb);
        }
      __syncthreads();

      // ---- layer 1 ----
      f32x4 acc1[8];
      #pragma unroll
      for (int gs = 0; gs < 8; ++gs) {
        float bz = db1v[gs];
        f32x4 v; v[0]=bz; v[1]=bz; v[2]=bz; v[3]=bz;
        acc1[gs] = v;
      }
      {
        #pragma unroll 2
        for (int it = 0; it < 8; ++it) {
          int k0i = (it + rot) & 7;
          bf16x8 af = ldh(h0n, col, k0i*4 + quad);
          const ushort* bp = B4 + k0i*4096;
          #pragma unroll
          for (int gs = 0; gs < 8; ++gs)
            acc1[gs] = __builtin_amdgcn_mfma_f32_16x16x32_bf16(
                af, *(const bf16x8*)(bp + gs*512), acc1[gs], 0, 0, 0);
        }
        const ushort* h1c = sh_h1[cur];
        #pragma unroll 2
        for (int it = 0; it < 8; ++it) {
          int k0i = (it + rot) & 7;
          bf16x8 af = ldh(h1c, col, k0i*4 + quad);
          const ushort* bp = B5 + k0i*4096;
          #pragma unroll
          for (int gs = 0; gs < 8; ++gs)
            acc1[gs] = __builtin_amdgcn_mfma_f32_16x16x32_bf16(
                af, *(const bf16x8*)(bp + gs*512), acc1[gs], 0, 0, 0);
        }
      }
      ushort* h1n = sh_h1[cur^1];
      #pragma unroll
      for (int st = 0; st < 2; ++st)
        #pragma unroll
        for (int r = 0; r < 4; ++r) {
          float iv = sig_(acc1[0+st][r]);
          float fv = sig_(acc1[2+st][r]);
          float gv = tanh_(acc1[4+st][r]);
          float ov = sig_(acc1[6+st][r]);
          float cn = fv*c1[st][r] + iv*gv;
          c1[st][r] = cn;
          float hn = ov*tanh_(cn);
          __bf16 hb = (__bf16)hn;
          h1n[swz32(quad*4+r, st*16 + n0)] = __builtin_bit_cast(ushort, hb);
        }
      __syncthreads();

      // ---- MLP layer 1 ----
      {
        f32x4 accp; accp[0]=bz1; accp[1]=bz1; accp[2]=bz1; accp[3]=bz1;
        const ushort* h1r = sh_h1[cur^1];
        #pragma unroll 2
        for (int it = 0; it < 8; ++it) {
          int k0i = (it + rot) & 7;
          bf16x8 af = ldh(h1r, col, k0i*4 + quad);
          accp = __builtin_amdgcn_mfma_f32_16x16x32_bf16(
              af, *(const bf16x8*)(B6 + k0i*512), accp, 0, 0, 0);
        }
        #pragma unroll
        for (int r = 0; r < 4; ++r) {
          float rv = fmaxf(accp[r], 0.0f);
          __bf16 rb = (__bf16)rv;
          sh_r[swz32(quad*4+r, wv*16 + col)] = __builtin_bit_cast(ushort, rb);
        }
      }
      __syncthreads();

      // ---- MLP layer 2 (wave 0 only) ----
      if (wv == 0) {
        f32x4 accq; accq[0]=0; accq[1]=0; accq[2]=0; accq[3]=0;
        #pragma unroll
        for (int it = 0; it < 4; ++it) {
          int k0i = (it + rot) & 3;
          bf16x8 af = ldh(sh_r, col, k0i*4 + quad);
          accq = __builtin_amdgcn_mfma_f32_16x16x32_bf16(
              af, *(const bf16x8*)(B7 + k0i*512), accq, 0, 0, 0);
        }
        if (col < 4) {
          float bo = bp2[col];
          #pragma unroll
          for (int r = 0; r < 4; ++r) {
            float p = sig_(accq[r] + bo);
            int b = quad*4 + r;
            sh_pred[b*4 + col] = p;
            out[((blk*BB + b)*TDEC + t)*4 + col] = p;
          }
        }
      }
      __syncthreads();
      cur ^= 1;
    }
  }
}

extern "C" void kernel_launch(void* const* d_in, const int* in_sizes, int n_in,
                              void* d_out, int out_size, void* d_ws, size_t ws_size,
                              hipStream_t stream) {
  (void)in_sizes; (void)n_in; (void)out_size;
  if (ws_size < (size_t)WS_ELEMS * sizeof(ushort)) return;

  const float* x      = (const float*)d_in[0];
  const float* eWih0  = (const float*)d_in[1];
  const float* eWhh0  = (const float*)d_in[2];
  const float* eb0    = (const float*)d_in[3];
  const float* eWih1  = (const float*)d_in[4];
  const float* eWhh1  = (const float*)d_in[5];
  const float* eb1    = (const float*)d_in[6];
  const float* dWih0  = (const float*)d_in[7];
  const float* dWhh0  = (const float*)d_in[8];
  const float* db0    = (const float*)d_in[9];
  const float* dWih1  = (const float*)d_in[10];
  const float* dWhh1  = (const float*)d_in[11];
  const float* db1    = (const float*)d_in[12];
  const float* Wp1    = (const float*)d_in[13];
  const float* bp1    = (const float*)d_in[14];
  const float* Wp2    = (const float*)d_in[15];
  const float* bp2    = (const float*)d_in[16];
  ushort* ws = (ushort*)d_ws;

  prep_kernel<<<WS_ELEMS/256, 256, 0, stream>>>(eWhh0, eWih1, eWhh1, dWhh0, dWih1, dWhh1,
                                                Wp1, Wp2, ws);
  lstm_all<<<256, NTH, 0, stream>>>(x, eWih0, eb0, eb1, dWih0, db0, db1,
                                    bp1, bp2, ws, (float*)d_out);
}